// Round 1
// 829.685 us; speedup vs baseline: 1.0554x; 1.0554x over previous
//
#include <hip/hip_runtime.h>
#include <stdint.h>

typedef float f2 __attribute__((ext_vector_type(2)));

// res[l] = floor(16 * b^l), b = exp((ln512 - ln16)/15) in fp32.
__constant__ float c_res[16] = {16.f, 20.f, 25.f, 32.f, 40.f, 50.f, 64.f, 80.f,
                                101.f, 128.f, 161.f, 203.f, 256.f, 322.f, 406.f, 512.f};

#define HASH_MASK ((1u << 19) - 1u)
#define P1 2654435761u
#define P2 805459861u
#define PTS_PER_THREAD 4

// Grid: 2 phases (levels 0-7, 8-15) x chunks x 8 levels; blockIdx%8 == level%8
// keeps one level's table per XCD L2 (round-robin dispatch), phase split keeps
// levels l and l+8 from being live together. PTS_PER_THREAD=4 -> 32 outstanding
// 8B gathers per wave before the first vmcnt wait (was 16): we are latency/MLP
// bound (0.29 req/cyc/CU achieved), so double the in-flight depth per wave.
// __launch_bounds__(256,4) pins the allocator to the <=128-VGPR tier so the
// 64 load-destination VGPRs (e[4][8]) don't drop us to the 8-waves/CU tier.
__global__ __launch_bounds__(256, 4) void hash_encode_kernel(
    const float* __restrict__ x,
    const float* __restrict__ tables,
    float* __restrict__ out,
    float* __restrict__ mask_out,
    int n_points,
    int blocks_per_phase)
{
    int bid = blockIdx.x;
    int level_base = 0;
    if (bid >= blocks_per_phase) { bid -= blocks_per_phase; level_base = 8; }
    int level = (bid & 7) + level_base;
    int chunk = bid >> 3;

    float res  = c_res[level];
    float grid = 1.0f / res;
    const f2* __restrict__ tab =
        (const f2*)tables + ((size_t)level << 19);   // 2^19 float2 per level

    int pbase = chunk * (256 * PTS_PER_THREAD) + threadIdx.x;

    uint32_t idx[PTS_PER_THREAD][8];
    float wx[PTS_PER_THREAD], wy[PTS_PER_THREAD], wz[PTS_PER_THREAD];
    bool valid[PTS_PER_THREAD];
    int pp[PTS_PER_THREAD];

    #pragma unroll
    for (int s = 0; s < PTS_PER_THREAD; ++s) {
        int p = pbase + s * 256;
        pp[s] = p;
        valid[s] = (p < n_points);
        int pc = valid[s] ? p : 0;

        float x0 = __builtin_nontemporal_load(&x[3 * (size_t)pc + 0]);
        float x1 = __builtin_nontemporal_load(&x[3 * (size_t)pc + 1]);
        float x2 = __builtin_nontemporal_load(&x[3 * (size_t)pc + 2]);

        if (level == 0 && valid[s]) {
            bool keep = (x0 >= 0.f) & (x0 <= 1.f) &
                        (x1 >= 0.f) & (x1 <= 1.f) &
                        (x2 >= 0.f) & (x2 <= 1.f);
            __builtin_nontemporal_store(keep ? 1.0f : 0.0f, &mask_out[pc]);
        }

        x0 = fminf(fmaxf(x0, 0.f), 1.f);
        x1 = fminf(fmaxf(x1, 0.f), 1.f);
        x2 = fminf(fmaxf(x2, 0.f), 1.f);

        float b0 = floorf(x0 / grid);
        float b1 = floorf(x1 / grid);
        float b2 = floorf(x2 / grid);

        wx[s] = (x0 - b0 * grid) / grid;
        wy[s] = (x1 - b1 * grid) / grid;
        wz[s] = (x2 - b2 * grid) / grid;

        uint32_t bx = (uint32_t)b0;
        uint32_t by = (uint32_t)b1;
        uint32_t bz = (uint32_t)b2;

        uint32_t hx0 = bx;        uint32_t hx1 = bx + 1u;
        uint32_t hy0 = by * P1;   uint32_t hy1 = hy0 + P1;
        uint32_t hz0 = bz * P2;   uint32_t hz1 = hz0 + P2;

        idx[s][0] = (hx0 ^ hy0 ^ hz0) & HASH_MASK;
        idx[s][1] = (hx0 ^ hy0 ^ hz1) & HASH_MASK;
        idx[s][2] = (hx0 ^ hy1 ^ hz0) & HASH_MASK;
        idx[s][3] = (hx0 ^ hy1 ^ hz1) & HASH_MASK;
        idx[s][4] = (hx1 ^ hy0 ^ hz0) & HASH_MASK;
        idx[s][5] = (hx1 ^ hy0 ^ hz1) & HASH_MASK;
        idx[s][6] = (hx1 ^ hy1 ^ hz0) & HASH_MASK;
        idx[s][7] = (hx1 ^ hy1 ^ hz1) & HASH_MASK;
    }

    // Issue all 32 gathers before any consumption.
    f2 e[PTS_PER_THREAD][8];
    #pragma unroll
    for (int s = 0; s < PTS_PER_THREAD; ++s)
        #pragma unroll
        for (int c = 0; c < 8; ++c)
            e[s][c] = tab[idx[s][c]];

    #pragma unroll
    for (int s = 0; s < PTS_PER_THREAD; ++s) {
        float owx = 1.f - wx[s], owy = 1.f - wy[s], owz = 1.f - wz[s];

        f2 c00 = e[s][0] * owx + e[s][4] * wx[s];
        f2 c01 = e[s][1] * owx + e[s][5] * wx[s];
        f2 c10 = e[s][2] * owx + e[s][6] * wx[s];
        f2 c11 = e[s][3] * owx + e[s][7] * wx[s];

        f2 c0 = c00 * owy + c10 * wy[s];
        f2 c1 = c01 * owy + c11 * wy[s];

        f2 cv = c0 * owz + c1 * wz[s];

        if (valid[s]) {
            f2* dst = (f2*)(out + (size_t)pp[s] * 32) + level;
            __builtin_nontemporal_store(cv, dst);
        }
    }
}

extern "C" void kernel_launch(void* const* d_in, const int* in_sizes, int n_in,
                              void* d_out, int out_size, void* d_ws, size_t ws_size,
                              hipStream_t stream) {
    const float* x      = (const float*)d_in[0];
    const float* tables = (const float*)d_in[1];
    float* out = (float*)d_out;
    int n_points = in_sizes[0] / 3;
    float* mask_out = out + (size_t)n_points * 32;

    int chunks = (n_points + 256 * PTS_PER_THREAD - 1) / (256 * PTS_PER_THREAD);
    int blocks_per_phase = chunks * 8;
    int blocks = blocks_per_phase * 2;
    hipLaunchKernelGGL(hash_encode_kernel, dim3(blocks), dim3(256), 0, stream,
                       x, tables, out, mask_out, n_points, blocks_per_phase);
}

// Round 2
// 804.883 us; speedup vs baseline: 1.0880x; 1.0308x over previous
//
#include <hip/hip_runtime.h>
#include <stdint.h>

typedef float f2 __attribute__((ext_vector_type(2)));
typedef float f4 __attribute__((ext_vector_type(4)));

// res[l] = floor(16 * b^l), b = exp((ln512 - ln16)/15) in fp32.
__constant__ float c_res[16] = {16.f, 20.f, 25.f, 32.f, 40.f, 50.f, 64.f, 80.f,
                                101.f, 128.f, 161.f, 203.f, 256.f, 322.f, 406.f, 512.f};

#define HASH_MASK ((1u << 19) - 1u)
#define P1 2654435761u
#define P2 805459861u
#define PTS_PER_THREAD 4

// Gather path is capped by ~64 outstanding L1 misses per CU (measured 0.29 and
// 0.31 lanes/cyc/CU across two very different MLP configs ~= 64 / 200cy L2
// latency). So the lever is FEWER misses, not more in-flight: the hash uses
// prime 1 on x, so when bx is even the (x, x+1) corner pair hashes to ADJACENT
// table entries (idx ^ 1) -> one 16B dwordx4 fetches both corners. 50% of
// points get 8x8B -> 4x16B (expected 6 requests/point-level, -25%).
__global__ __launch_bounds__(256, 4) void hash_encode_kernel(
    const float* __restrict__ x,
    const float* __restrict__ tables,
    float* __restrict__ out,
    float* __restrict__ mask_out,
    int n_points,
    int blocks_per_phase)
{
    int bid = blockIdx.x;
    int level_base = 0;
    if (bid >= blocks_per_phase) { bid -= blocks_per_phase; level_base = 8; }
    int level = (bid & 7) + level_base;
    int chunk = bid >> 3;

    float res  = c_res[level];
    float grid = 1.0f / res;
    const f2* __restrict__ tab =
        (const f2*)tables + ((size_t)level << 19);   // 2^19 float2 per level
    const f4* __restrict__ tab4 = (const f4*)tab;    // 2^18 float4 per level

    int pbase = chunk * (256 * PTS_PER_THREAD) + threadIdx.x;

    uint32_t idx[PTS_PER_THREAD][8];
    float wx[PTS_PER_THREAD], wy[PTS_PER_THREAD], wz[PTS_PER_THREAD];
    bool valid[PTS_PER_THREAD];
    bool bxodd[PTS_PER_THREAD];
    int pp[PTS_PER_THREAD];

    #pragma unroll
    for (int s = 0; s < PTS_PER_THREAD; ++s) {
        int p = pbase + s * 256;
        pp[s] = p;
        valid[s] = (p < n_points);
        int pc = valid[s] ? p : 0;

        float x0 = __builtin_nontemporal_load(&x[3 * (size_t)pc + 0]);
        float x1 = __builtin_nontemporal_load(&x[3 * (size_t)pc + 1]);
        float x2 = __builtin_nontemporal_load(&x[3 * (size_t)pc + 2]);

        if (level == 0 && valid[s]) {
            bool keep = (x0 >= 0.f) & (x0 <= 1.f) &
                        (x1 >= 0.f) & (x1 <= 1.f) &
                        (x2 >= 0.f) & (x2 <= 1.f);
            __builtin_nontemporal_store(keep ? 1.0f : 0.0f, &mask_out[pc]);
        }

        x0 = fminf(fmaxf(x0, 0.f), 1.f);
        x1 = fminf(fmaxf(x1, 0.f), 1.f);
        x2 = fminf(fmaxf(x2, 0.f), 1.f);

        // Keep the exact fp32 sequence of the verified kernel (floor(x/grid)),
        // grid = 1/res: changing to x*res can flip buckets by 1 ulp.
        float b0 = floorf(x0 / grid);
        float b1 = floorf(x1 / grid);
        float b2 = floorf(x2 / grid);

        wx[s] = (x0 - b0 * grid) / grid;
        wy[s] = (x1 - b1 * grid) / grid;
        wz[s] = (x2 - b2 * grid) / grid;

        uint32_t bx = (uint32_t)b0;
        uint32_t by = (uint32_t)b1;
        uint32_t bz = (uint32_t)b2;

        bxodd[s] = (bx & 1u) != 0u;

        uint32_t hx0 = bx;        uint32_t hx1 = bx + 1u;
        uint32_t hy0 = by * P1;   uint32_t hy1 = hy0 + P1;
        uint32_t hz0 = bz * P2;   uint32_t hz1 = hz0 + P2;

        idx[s][0] = (hx0 ^ hy0 ^ hz0) & HASH_MASK;
        idx[s][1] = (hx0 ^ hy0 ^ hz1) & HASH_MASK;
        idx[s][2] = (hx0 ^ hy1 ^ hz0) & HASH_MASK;
        idx[s][3] = (hx0 ^ hy1 ^ hz1) & HASH_MASK;
        idx[s][4] = (hx1 ^ hy0 ^ hz0) & HASH_MASK;
        idx[s][5] = (hx1 ^ hy0 ^ hz1) & HASH_MASK;
        idx[s][6] = (hx1 ^ hy1 ^ hz0) & HASH_MASK;
        idx[s][7] = (hx1 ^ hy1 ^ hz1) & HASH_MASK;
    }

    // Issue all gathers before any consumption. Even-bx lanes: 4x16B paired
    // loads (idx[j] and idx[j]^1 == idx[j+4] share a float4). Odd-bx lanes:
    // 8x8B as before. Divergent if/else -> loads are exec-masked, so a mixed
    // wave issues 4 insts for even lanes + 8 for odd lanes, each lane
    // contributing only its own requests.
    f2 e[PTS_PER_THREAD][8];
    #pragma unroll
    for (int s = 0; s < PTS_PER_THREAD; ++s) {
        if (!bxodd[s]) {
            #pragma unroll
            for (int j = 0; j < 4; ++j) {
                uint32_t q = idx[s][j];
                f4 v = tab4[q >> 1];
                f2 lov = {v.x, v.y};
                f2 hiv = {v.z, v.w};
                bool hi = (q & 1u) != 0u;
                e[s][j]     = hi ? hiv : lov;   // entry q     (x = bx)
                e[s][j + 4] = hi ? lov : hiv;   // entry q ^ 1 (x = bx+1)
            }
        } else {
            #pragma unroll
            for (int c = 0; c < 8; ++c)
                e[s][c] = tab[idx[s][c]];
        }
    }

    #pragma unroll
    for (int s = 0; s < PTS_PER_THREAD; ++s) {
        float owx = 1.f - wx[s], owy = 1.f - wy[s], owz = 1.f - wz[s];

        f2 c00 = e[s][0] * owx + e[s][4] * wx[s];
        f2 c01 = e[s][1] * owx + e[s][5] * wx[s];
        f2 c10 = e[s][2] * owx + e[s][6] * wx[s];
        f2 c11 = e[s][3] * owx + e[s][7] * wx[s];

        f2 c0 = c00 * owy + c10 * wy[s];
        f2 c1 = c01 * owy + c11 * wy[s];

        f2 cv = c0 * owz + c1 * wz[s];

        if (valid[s]) {
            f2* dst = (f2*)(out + (size_t)pp[s] * 32) + level;
            __builtin_nontemporal_store(cv, dst);
        }
    }
}

extern "C" void kernel_launch(void* const* d_in, const int* in_sizes, int n_in,
                              void* d_out, int out_size, void* d_ws, size_t ws_size,
                              hipStream_t stream) {
    const float* x      = (const float*)d_in[0];
    const float* tables = (const float*)d_in[1];
    float* out = (float*)d_out;
    int n_points = in_sizes[0] / 3;
    float* mask_out = out + (size_t)n_points * 32;

    int chunks = (n_points + 256 * PTS_PER_THREAD - 1) / (256 * PTS_PER_THREAD);
    int blocks_per_phase = chunks * 8;
    int blocks = blocks_per_phase * 2;
    hipLaunchKernelGGL(hash_encode_kernel, dim3(blocks), dim3(256), 0, stream,
                       x, tables, out, mask_out, n_points, blocks_per_phase);
}